// Round 8
// baseline (217.061 us; speedup 1.0000x reference)
//
#include <hip/hip_runtime.h>
#include <hip/hip_bf16.h>

// StackedAdapter: out[b] = x[b] + W2[g]^T·relu(W1[g]^T·LN(x[b]) + B1[g]) + B2[g]
// B=32, S=512, D=1024, F=2048. 16384 tokens, 4096 per group, 4 groups.

#define S_DIM 512
#define D_DIM 1024
#define F_DIM 2048
#define MPG   4096

typedef __attribute__((ext_vector_type(8)))  short short8;   // 8 bf16
typedef __attribute__((ext_vector_type(4)))  float f32x4;
typedef __attribute__((ext_vector_type(16))) float f32x16;

__device__ __forceinline__ void gll16(const void* g, void* l) {
  __builtin_amdgcn_global_load_lds((__attribute__((address_space(1))) void*)g,
                                   (__attribute__((address_space(3))) void*)l,
                                   16, 0, 0);
}
#define VMC0()  asm volatile("s_waitcnt vmcnt(0)" ::: "memory")
#define SB()    __builtin_amdgcn_sched_barrier(0)
#define BAR()   __builtin_amdgcn_s_barrier()

// ---------------------------------------------------------------------------
// Kernel 1 (merged): weight transpose-cast  +  LayerNorm/gather.
// ---------------------------------------------------------------------------
__global__ __launch_bounds__(256) void prep_kernel(
    const float* __restrict__ W1, const float* __restrict__ W2,
    const float* __restrict__ x,  const int* __restrict__ idx,
    const float* __restrict__ G,  const float* __restrict__ Bn,
    __hip_bfloat16* __restrict__ W1t, __hip_bfloat16* __restrict__ W2t,
    __hip_bfloat16* __restrict__ Xn)
{
  __shared__ float tl[32][33];
  const int bid = blockIdx.x;
  if (bid < 16384) {
    const float* src; __hip_bfloat16* dst;
    int R, C, tr, tc;
    if (bid < 8192) {                 // W1: [4][1024][2048] -> [4][2048][1024]
      const int g = bid >> 11, t = bid & 2047;
      R = 1024; C = 2048; tr = t >> 6; tc = t & 63;
      src = W1 + (size_t)g * R * C;
      dst = W1t + (size_t)g * R * C;
    } else {                          // W2: [4][2048][1024] -> [4][1024][2048]
      const int b2 = bid - 8192;
      const int g = b2 >> 11, t = b2 & 2047;
      R = 2048; C = 1024; tr = t >> 5; tc = t & 31;
      src = W2 + (size_t)g * R * C;
      dst = W2t + (size_t)g * R * C;
    }
    const int tx = threadIdx.x & 31, ty = threadIdx.x >> 5;
    const int r0 = tr * 32, c0 = tc * 32;
#pragma unroll
    for (int i = 0; i < 4; ++i)
      tl[ty + 8 * i][tx] = src[(size_t)(r0 + ty + 8 * i) * C + (c0 + tx)];
    __syncthreads();
#pragma unroll
    for (int i = 0; i < 4; ++i)
      dst[(size_t)(c0 + ty + 8 * i) * R + (r0 + tx)] = __float2bfloat16(tl[tx][ty + 8 * i]);
    return;
  }
  // ---- LayerNorm + gather ----
  const int lb   = bid - 16384;
  const int wid  = lb * 4 + (threadIdx.x >> 6);
  const int lane = threadIdx.x & 63;
  const int g = wid >> 12;
  const int r = wid & 4095;
  const int j = r >> 9;
  const int tok = r & 511;
  const int b = idx[g * 8 + j];

  const float* src = x + ((size_t)b * S_DIM + tok) * D_DIM + lane * 16;
  float4 vq[4];
#pragma unroll
  for (int i = 0; i < 4; ++i) vq[i] = ((const float4*)src)[i];
  const float* va = (const float*)vq;

  float s = 0.f, s2 = 0.f;
#pragma unroll
  for (int i = 0; i < 16; ++i) { s += va[i]; s2 += va[i] * va[i]; }
#pragma unroll
  for (int o = 32; o > 0; o >>= 1) { s += __shfl_xor(s, o); s2 += __shfl_xor(s2, o); }

  const float mu  = s * (1.0f / 1024.0f);
  float var = fmaxf(s2 * (1.0f / 1024.0f) - mu * mu, 0.0f) * (1024.0f / 1023.0f);
  const float rs  = 1.0f / (sqrtf(var) + 1e-6f);

  float4 gq[4], bq[4];
  const float* gp = G  + (size_t)g * D_DIM + lane * 16;
  const float* bp = Bn + (size_t)g * D_DIM + lane * 16;
#pragma unroll
  for (int i = 0; i < 4; ++i) { gq[i] = ((const float4*)gp)[i]; bq[i] = ((const float4*)bp)[i]; }
  const float* ga = (const float*)gq;
  const float* be = (const float*)bq;

  __align__(16) __hip_bfloat16 ob[16];
#pragma unroll
  for (int i = 0; i < 16; ++i)
    ob[i] = __float2bfloat16(ga[i] * (va[i] - mu) * rs + be[i]);

  __hip_bfloat16* dst = Xn + ((size_t)g * MPG + r) * D_DIM + lane * 16;
  ((uint4*)dst)[0] = *(const uint4*)&ob[0];
  ((uint4*)dst)[1] = *(const uint4*)&ob[8];
}

// ---------------------------------------------------------------------------
// Kernels 2/3: bf16 MFMA GEMM with 32x32x16 shape (µbench 2382 vs 2075 TF,
// half the MFMA instruction count & lgkm waits at identical LDS traffic).
// BM=BN=256, BK=64, 8 waves (2Mx4N, per-wave 128x64 via 4x2 tiles of 32x32).
// R6 2-phase rhythm (best measured): per K-tile ONE vmcnt(0) + ONE barrier:
//   ph1: vmcnt(0); s_barrier; read all B frags + A frags (mtiles 0,1);
//        16 MFMA.    ph2: stage tile t+1 (8 gll); read A (mtiles 2,3); 16 MFMA.
//
// LDS 2x64KB buffers: planes {A kh0 @0, B kh0 @16K, A kh1 @32K, B kh1 @48K},
// plane = 256 rows x 32 k; line(128B) = row-pair; slot permutation
//   phys_slot(r,s) = ((r&1)*4+s) ^ ((r>>1)&7)
// read-side + inverse on global source, LDS dest linear (rule 21).
// 32x32 frag reads: 16-lane phase groups hit 2 lanes/slot => conflict-free
// (same algebra as the 16x16 path that measured SQ_LDS_BANK_CONFLICT=0).
// A/B frag: row=lane&31, k=(lane>>5)*8+j.  C/D [m74/m101]:
// col=lane&31, row=(reg&3)+8*(reg>>2)+4*(lane>>5).
// ---------------------------------------------------------------------------
template <bool SECOND>
__global__ __launch_bounds__(512, 2) void gemm_kernel(
    const __hip_bfloat16* __restrict__ A,
    const __hip_bfloat16* __restrict__ Bw,
    const float* __restrict__ bias,
    const float* __restrict__ xres,
    const int* __restrict__ idx,
    __hip_bfloat16* __restrict__ obf,
    float* __restrict__ of32,
    const int N, const int K, const int NT)
{
  extern __shared__ char lds[];        // 131072 bytes
  const int ntile = N >> 8;
  const int nwg = gridDim.x;
  const int bid0 = blockIdx.x;
  const int bid = (bid0 & 7) * (nwg >> 3) + (bid0 >> 3);   // XCD-contiguous
  const int mt = bid / ntile, nt = bid % ntile;
  const int g  = mt >> 4;
  const int tid = threadIdx.x;
  const int w = tid >> 6, lane = tid & 63;
  const int wm = w >> 2, wn = w & 3;

  const __hip_bfloat16* Ab = A + (size_t)mt * 256 * K;
  const __hip_bfloat16* Bb = Bw + ((size_t)g * N + (size_t)nt * 256) * K;

  // staging decode: inverse slot permutation on the global source address
  const int sp   = (lane & 7) ^ ((lane >> 3) & 7);
  const int srow = 2 * (lane >> 3) + (sp >> 2);
  const int skof = (sp & 3) * 8;
  const __hip_bfloat16* Ag0 = Ab + (size_t)(w * 32 + srow) * K + skof;
  const __hip_bfloat16* Ag1 = Ag0 + (size_t)16 * K;
  const __hip_bfloat16* Bg0 = Bb + (size_t)(w * 32 + srow) * K + skof;
  const __hip_bfloat16* Bg1 = Bg0 + (size_t)16 * K;

  // read-side lane constants for 32x32 frags: base row = lane&31,
  // k = khalf*8 + j (khalf = lane>>5); 16B slot s = k16*2 + khalf.
  const int l31 = lane & 31, khalf = lane >> 5;
  const int sp_lo = (((l31 & 1) << 2) + khalf)     ^ ((l31 >> 1) & 7);
  const int sp_hi = (((l31 & 1) << 2) + 2 + khalf) ^ ((l31 >> 1) & 7);
  const int aoff_lo = ((l31 >> 1) << 7) + (sp_lo << 4);   // k16=0
  const int aoff_hi = ((l31 >> 1) << 7) + (sp_hi << 4);   // k16=1

  f32x16 acc[4][2] = {};               // [mtile][ntile] (4x2 of 32x32)
  short8 fa[2][4], fb[2][4];           // [mt2|nt][kc = kh*2+k16]

#define STAGE4(BUFX, TN) {                                                  \
    const int k0 = (TN) * 64;                                               \
    char* d0 = lds + (BUFX) + w * 2048;                                     \
    gll16(Ag0 + k0,      d0);         gll16(Ag1 + k0,      d0 + 1024);      \
    gll16(Bg0 + k0,      d0 + 16384); gll16(Bg1 + k0,      d0 + 17408);     \
    gll16(Ag0 + k0 + 32, d0 + 32768); gll16(Ag1 + k0 + 32, d0 + 33792);     \
    gll16(Bg0 + k0 + 32, d0 + 49152); gll16(Bg1 + k0 + 32, d0 + 50176); }

  // A plane base: BUFB + kh*32768 + wm*8192 + mtile*2048
  // B plane base: BUFB + 16384 + kh*32768 + wn*4096 + ntile*2048
#define RDA(BUFB, MH) {                                                     \
    _Pragma("unroll") for (int m2 = 0; m2 < 2; ++m2)                        \
      _Pragma("unroll") for (int kc = 0; kc < 4; ++kc) {                    \
        const char* b_ = lds + (BUFB) + (kc >> 1) * 32768 + wm * 8192 +     \
                         ((MH) * 2 + m2) * 2048 +                           \
                         ((kc & 1) ? aoff_hi : aoff_lo);                    \
        fa[m2][kc] = *(const short8*)b_; } }

#define RDB(BUFB) {                                                         \
    _Pragma("unroll") for (int n2 = 0; n2 < 2; ++n2)                        \
      _Pragma("unroll") for (int kc = 0; kc < 4; ++kc) {                    \
        const char* b_ = lds + (BUFB) + 16384 + (kc >> 1) * 32768 +         \
                         wn * 4096 + n2 * 2048 +                            \
                         ((kc & 1) ? aoff_hi : aoff_lo);                    \
        fb[n2][kc] = *(const short8*)b_; } }

#define MF(MH) {                                                            \
    __builtin_amdgcn_s_setprio(1);                                          \
    _Pragma("unroll") for (int kc = 0; kc < 4; ++kc)                        \
      _Pragma("unroll") for (int m2 = 0; m2 < 2; ++m2)                      \
        _Pragma("unroll") for (int n2 = 0; n2 < 2; ++n2)                    \
          acc[(MH) * 2 + m2][n2] = __builtin_amdgcn_mfma_f32_32x32x16_bf16( \
              fa[m2][kc], fb[n2][kc], acc[(MH) * 2 + m2][n2], 0, 0, 0);     \
    __builtin_amdgcn_s_setprio(0); }

  // prologue: stage tile 0 into buffer 0
  STAGE4(0, 0);

  for (int t = 0; t < NT; ++t) {
    const int bufb = (t & 1) << 16;
    const int bufx = bufb ^ 65536;
    // ph1: drain own glls, rendezvous, consume mtiles 0,1 over full K=64
    VMC0();
    BAR();
    SB();
    RDB(bufb);
    RDA(bufb, 0);
    MF(0);
    // ph2: prefetch tile t+1 (no sync), consume mtiles 2,3
    if (t + 1 < NT) STAGE4(bufx, t + 1);
    RDA(bufb, 1);
    MF(1);
  }
#undef STAGE4
#undef RDA
#undef RDB
#undef MF

  BAR();   // staging planes dead; epilogue overlays buffer 0

  // -------- coalesced epilogue (per-wave 32x33-padded f32 slice) ----------
  float* wsl = (float*)(lds + w * 4352);       // 32 rows x stride 33 (4224B)
  const int rr2 = lane >> 1;                   // 0..31
  const int cb  = (lane & 1) * 16;             // 0 / 16

  float bvv[2];
#pragma unroll
  for (int n2 = 0; n2 < 2; ++n2)
    bvv[n2] = bias[(size_t)g * N + nt * 256 + wn * 64 + n2 * 32 + l31];

  const int rbase = (mt & 15) * 256;
  const int bsc = SECOND ? idx[g * 8 + (rbase >> 9)] : 0;
  const size_t obase = (size_t)bsc * S_DIM * D_DIM;

#pragma unroll
  for (int m2 = 0; m2 < 4; ++m2) {
#pragma unroll
    for (int n2 = 0; n2 < 2; ++n2) {
      // scatter acc tile (C/D layout) into LDS with bias (+relu for GEMM1)
#pragma unroll
      for (int rg = 0; rg < 16; ++rg) {
        const int row = (rg & 3) + 8 * (rg >> 2) + 4 * khalf;
        float v = acc[m2][n2][rg] + bvv[n2];
        if (!SECOND) v = fmaxf(v, 0.0f);
        wsl[row * 33 + l31] = v;
      }
      const int gcol = nt * 256 + wn * 64 + n2 * 32 + cb;
      if constexpr (!SECOND) {
        const int grow = mt * 256 + wm * 128 + m2 * 32 + rr2;
        float4 v0 = *(const float4*)&wsl[rr2 * 33 + cb];
        float4 v1 = *(const float4*)&wsl[rr2 * 33 + cb + 4];
        float4 v2 = *(const float4*)&wsl[rr2 * 33 + cb + 8];
        float4 v3 = *(const float4*)&wsl[rr2 * 33 + cb + 12];
        __align__(16) __hip_bfloat16 ob[16];
        ob[0]=__float2bfloat16(v0.x); ob[1]=__float2bfloat16(v0.y);
        ob[2]=__float2bfloat16(v0.z); ob[3]=__float2bfloat16(v0.w);
        ob[4]=__float2bfloat16(v1.x); ob[5]=__float2bfloat16(v1.y);
        ob[6]=__float2bfloat16(v1.z); ob[7]=__float2bfloat16(v1.w);
        ob[8]=__float2bfloat16(v2.x); ob[9]=__float2bfloat16(v2.y);
        ob[10]=__float2bfloat16(v2.z); ob[11]=__float2bfloat16(v2.w);
        ob[12]=__float2bfloat16(v3.x); ob[13]=__float2bfloat16(v3.y);
        ob[14]=__float2bfloat16(v3.z); ob[15]=__float2bfloat16(v3.w);
        *(uint4*)&obf[(size_t)grow * N + gcol]     = *(const uint4*)&ob[0];
        *(uint4*)&obf[(size_t)grow * N + gcol + 8] = *(const uint4*)&ob[8];
      } else {
        const int rloc = rbase + wm * 128 + m2 * 32 + rr2;
        const int tok = rloc & 511;
        const size_t off = obase + (size_t)tok * D_DIM + gcol;
        float4 v0 = *(const float4*)&wsl[rr2 * 33 + cb];
        float4 v1 = *(const float4*)&wsl[rr2 * 33 + cb + 4];
        float4 v2 = *(const float4*)&wsl[rr2 * 33 + cb + 8];
        float4 v3 = *(const float4*)&wsl[rr2 * 33 + cb + 12];
        float4 x0 = *(const float4*)&xres[off];
        float4 x1 = *(const float4*)&xres[off + 4];
        float4 x2 = *(const float4*)&xres[off + 8];
        float4 x3 = *(const float4*)&xres[off + 12];
        v0.x+=x0.x; v0.y+=x0.y; v0.z+=x0.z; v0.w+=x0.w;
        v1.x+=x1.x; v1.y+=x1.y; v1.z+=x1.z; v1.w+=x1.w;
        v2.x+=x2.x; v2.y+=x2.y; v2.z+=x2.z; v2.w+=x2.w;
        v3.x+=x3.x; v3.y+=x3.y; v3.z+=x3.z; v3.w+=x3.w;
        *(float4*)&of32[off]      = v0;
        *(float4*)&of32[off + 4]  = v1;
        *(float4*)&of32[off + 8]  = v2;
        *(float4*)&of32[off + 12] = v3;
      }
    }
  }
}

// ---------------------------------------------------------------------------
extern "C" void kernel_launch(void* const* d_in, const int* in_sizes, int n_in,
                              void* d_out, int out_size, void* d_ws, size_t ws_size,
                              hipStream_t stream) {
  const float* x  = (const float*)d_in[0];
  const int*   idx = (const int*)d_in[1];
  const float* W1 = (const float*)d_in[2];
  const float* B1 = (const float*)d_in[3];
  const float* W2 = (const float*)d_in[4];
  const float* B2 = (const float*)d_in[5];
  const float* G  = (const float*)d_in[6];
  const float* Bn = (const float*)d_in[7];
  float* out = (float*)d_out;

  char* ws = (char*)d_ws;
  __hip_bfloat16* Xn  = (__hip_bfloat16*)(ws);                    // 32 MiB
  __hip_bfloat16* W1t = (__hip_bfloat16*)(ws + 33554432);         // 16 MiB
  __hip_bfloat16* W2t = (__hip_bfloat16*)(ws + 50331648);         // 16 MiB
  __hip_bfloat16* H1  = (__hip_bfloat16*)(ws + 67108864);         // 64 MiB

  (void)hipFuncSetAttribute((const void*)gemm_kernel<false>,
                            hipFuncAttributeMaxDynamicSharedMemorySize, 131072);
  (void)hipFuncSetAttribute((const void*)gemm_kernel<true>,
                            hipFuncAttributeMaxDynamicSharedMemorySize, 131072);

  prep_kernel<<<dim3(20480), dim3(256), 0, stream>>>(
      W1, W2, x, idx, G, Bn, W1t, W2t, Xn);
  gemm_kernel<false><<<dim3(512), dim3(512), 131072, stream>>>(
      Xn, W1t, B1, nullptr, nullptr, H1, nullptr, F_DIM, D_DIM, 16);
  gemm_kernel<true><<<dim3(256), dim3(512), 131072, stream>>>(
      H1, W2t, B2, x, idx, nullptr, out, D_DIM, F_DIM, 32);
}

// Round 9
// 217.017 us; speedup vs baseline: 1.0002x; 1.0002x over previous
//
#include <hip/hip_runtime.h>
#include <hip/hip_bf16.h>

// StackedAdapter: out[b] = x[b] + W2[g]^T·relu(W1[g]^T·LN(x[b]) + B1[g]) + B2[g]
// B=32, S=512, D=1024, F=2048. 16384 tokens, 4096 per group, 4 groups.

#define S_DIM 512
#define D_DIM 1024
#define F_DIM 2048
#define MPG   4096

typedef __attribute__((ext_vector_type(8)))  short short8;   // 8 bf16
typedef __attribute__((ext_vector_type(4)))  float f32x4;
typedef __attribute__((ext_vector_type(16))) float f32x16;

__device__ __forceinline__ void gll16(const void* g, void* l) {
  __builtin_amdgcn_global_load_lds((__attribute__((address_space(1))) void*)g,
                                   (__attribute__((address_space(3))) void*)l,
                                   16, 0, 0);
}
#define VMC0()  asm volatile("s_waitcnt vmcnt(0)" ::: "memory")
#define SB()    __builtin_amdgcn_sched_barrier(0)
#define BAR()   __builtin_amdgcn_s_barrier()

// ---------------------------------------------------------------------------
// Kernel 1 (merged): weight transpose-cast  +  LayerNorm/gather.
// ---------------------------------------------------------------------------
__global__ __launch_bounds__(256) void prep_kernel(
    const float* __restrict__ W1, const float* __restrict__ W2,
    const float* __restrict__ x,  const int* __restrict__ idx,
    const float* __restrict__ G,  const float* __restrict__ Bn,
    __hip_bfloat16* __restrict__ W1t, __hip_bfloat16* __restrict__ W2t,
    __hip_bfloat16* __restrict__ Xn)
{
  __shared__ float tl[32][33];
  const int bid = blockIdx.x;
  if (bid < 16384) {
    const float* src; __hip_bfloat16* dst;
    int R, C, tr, tc;
    if (bid < 8192) {                 // W1: [4][1024][2048] -> [4][2048][1024]
      const int g = bid >> 11, t = bid & 2047;
      R = 1024; C = 2048; tr = t >> 6; tc = t & 63;
      src = W1 + (size_t)g * R * C;
      dst = W1t + (size_t)g * R * C;
    } else {                          // W2: [4][2048][1024] -> [4][1024][2048]
      const int b2 = bid - 8192;
      const int g = b2 >> 11, t = b2 & 2047;
      R = 2048; C = 1024; tr = t >> 5; tc = t & 31;
      src = W2 + (size_t)g * R * C;
      dst = W2t + (size_t)g * R * C;
    }
    const int tx = threadIdx.x & 31, ty = threadIdx.x >> 5;
    const int r0 = tr * 32, c0 = tc * 32;
#pragma unroll
    for (int i = 0; i < 4; ++i)
      tl[ty + 8 * i][tx] = src[(size_t)(r0 + ty + 8 * i) * C + (c0 + tx)];
    __syncthreads();
#pragma unroll
    for (int i = 0; i < 4; ++i)
      dst[(size_t)(c0 + ty + 8 * i) * R + (r0 + tx)] = __float2bfloat16(tl[tx][ty + 8 * i]);
    return;
  }
  // ---- LayerNorm + gather ----
  const int lb   = bid - 16384;
  const int wid  = lb * 4 + (threadIdx.x >> 6);
  const int lane = threadIdx.x & 63;
  const int g = wid >> 12;
  const int r = wid & 4095;
  const int j = r >> 9;
  const int tok = r & 511;
  const int b = idx[g * 8 + j];

  const float* src = x + ((size_t)b * S_DIM + tok) * D_DIM + lane * 16;
  float4 vq[4];
#pragma unroll
  for (int i = 0; i < 4; ++i) vq[i] = ((const float4*)src)[i];
  const float* va = (const float*)vq;

  float s = 0.f, s2 = 0.f;
#pragma unroll
  for (int i = 0; i < 16; ++i) { s += va[i]; s2 += va[i] * va[i]; }
#pragma unroll
  for (int o = 32; o > 0; o >>= 1) { s += __shfl_xor(s, o); s2 += __shfl_xor(s2, o); }

  const float mu  = s * (1.0f / 1024.0f);
  float var = fmaxf(s2 * (1.0f / 1024.0f) - mu * mu, 0.0f) * (1024.0f / 1023.0f);
  const float rs  = 1.0f / (sqrtf(var) + 1e-6f);

  float4 gq[4], bq[4];
  const float* gp = G  + (size_t)g * D_DIM + lane * 16;
  const float* bp = Bn + (size_t)g * D_DIM + lane * 16;
#pragma unroll
  for (int i = 0; i < 4; ++i) { gq[i] = ((const float4*)gp)[i]; bq[i] = ((const float4*)bp)[i]; }
  const float* ga = (const float*)gq;
  const float* be = (const float*)bq;

  __align__(16) __hip_bfloat16 ob[16];
#pragma unroll
  for (int i = 0; i < 16; ++i)
    ob[i] = __float2bfloat16(ga[i] * (va[i] - mu) * rs + be[i]);

  __hip_bfloat16* dst = Xn + ((size_t)g * MPG + r) * D_DIM + lane * 16;
  ((uint4*)dst)[0] = *(const uint4*)&ob[0];
  ((uint4*)dst)[1] = *(const uint4*)&ob[8];
}

// ---------------------------------------------------------------------------
// Kernels 2/3: bf16 MFMA GEMM, 32x32x16 shape, BM=BN=256, BK=64, 8 waves
// (2Mx4N; per-wave 128x64 via 4x2 tiles of 32x32). R6 2-phase rhythm.
//
// LDS 2x64KB buffers: planes {A kh0 @0, B kh0 @16K, A kh1 @32K, B kh1 @48K};
// plane = 256 rows x 32 k; 128B line = row-pair (2 rows x 4 slots of 8k).
// Slot permutation (FIXED vs R8): logical slot = (r&1)*4 + k16*2 + khalf;
//   phys = logical ^ Xl,  Xl = (line&7) ^ (((line>>3)&1)<<1)
// The line-bit-3 term de-aliases lanes 16 apart (R8: same (line&7,slot)
// cell => 4 lanes/bank => 6.29e6 conflicts). With it, every 16-lane group
// hits each slot exactly 2x and cells are globally distinct.
// Staging inverse (LDS dest linear, rule 21): gll#0 (lines 0-7):
//   sp=(l&7)^(l>>3); srow=2*(l>>3)+(sp>>2); skof=(sp&3)*8
// gll#1 (lines 8-15): Xl has extra ^2 => source row srow+16, k = skof^16.
// A/B frag: row=lane&31, k=(lane>>5)*8+j.  C/D [m74/m101]:
// col=lane&31, row=(reg&3)+8*(reg>>2)+4*(lane>>5).
// ---------------------------------------------------------------------------
template <bool SECOND>
__global__ __launch_bounds__(512, 2) void gemm_kernel(
    const __hip_bfloat16* __restrict__ A,
    const __hip_bfloat16* __restrict__ Bw,
    const float* __restrict__ bias,
    const float* __restrict__ xres,
    const int* __restrict__ idx,
    __hip_bfloat16* __restrict__ obf,
    float* __restrict__ of32,
    const int N, const int K, const int NT)
{
  extern __shared__ char lds[];        // 131072 bytes
  const int ntile = N >> 8;
  const int nwg = gridDim.x;
  const int bid0 = blockIdx.x;
  const int bid = (bid0 & 7) * (nwg >> 3) + (bid0 >> 3);   // XCD-contiguous
  const int mt = bid / ntile, nt = bid % ntile;
  const int g  = mt >> 4;
  const int tid = threadIdx.x;
  const int w = tid >> 6, lane = tid & 63;
  const int wm = w >> 2, wn = w & 3;

  const __hip_bfloat16* Ab = A + (size_t)mt * 256 * K;
  const __hip_bfloat16* Bb = Bw + ((size_t)g * N + (size_t)nt * 256) * K;

  // staging decode: inverse slot permutation on the global source address
  const int sp    = (lane & 7) ^ (lane >> 3);
  const int srow  = 2 * (lane >> 3) + (sp >> 2);
  const int skof  = (sp & 3) * 8;
  const int skof2 = ((sp & 3) ^ 2) * 8;        // gll#1: k offset XOR 16
  const __hip_bfloat16* Ag0 = Ab + (size_t)(w * 32 + srow) * K + skof;
  const __hip_bfloat16* Ag1 = Ab + (size_t)(w * 32 + srow + 16) * K + skof2;
  const __hip_bfloat16* Bg0 = Bb + (size_t)(w * 32 + srow) * K + skof;
  const __hip_bfloat16* Bg1 = Bb + (size_t)(w * 32 + srow + 16) * K + skof2;

  // read-side lane constants for 32x32 frags
  const int l31 = lane & 31, khalf = lane >> 5;
  const int Xl = ((l31 >> 1) & 7) ^ (((l31 >> 4) & 1) << 1);
  const int sp_lo = (((l31 & 1) << 2) | khalf) ^ Xl;         // k16=0
  const int sp_hi = (((l31 & 1) << 2) | 2 | khalf) ^ Xl;     // k16=1
  const int aoff_lo = ((l31 >> 1) << 7) + (sp_lo << 4);
  const int aoff_hi = ((l31 >> 1) << 7) + (sp_hi << 4);

  f32x16 acc[4][2] = {};               // [mtile][ntile] (4x2 of 32x32)
  short8 fa[2][4], fb[2][4];           // [sub][kc = kh*2+k16]

#define STAGE4(BUFX, TN) {                                                  \
    const int k0 = (TN) * 64;                                               \
    char* d0 = lds + (BUFX) + w * 2048;                                     \
    gll16(Ag0 + k0,      d0);         gll16(Ag1 + k0,      d0 + 1024);      \
    gll16(Bg0 + k0,      d0 + 16384); gll16(Bg1 + k0,      d0 + 17408);     \
    gll16(Ag0 + k0 + 32, d0 + 32768); gll16(Ag1 + k0 + 32, d0 + 33792);     \
    gll16(Bg0 + k0 + 32, d0 + 49152); gll16(Bg1 + k0 + 32, d0 + 50176); }

#define RDA(BUFB, MH) {                                                     \
    _Pragma("unroll") for (int m2 = 0; m2 < 2; ++m2)                        \
      _Pragma("unroll") for (int kc = 0; kc < 4; ++kc) {                    \
        const char* b_ = lds + (BUFB) + (kc >> 1) * 32768 + wm * 8192 +     \
                         ((MH) * 2 + m2) * 2048 +                           \
                         ((kc & 1) ? aoff_hi : aoff_lo);                    \
        fa[m2][kc] = *(const short8*)b_; } }

#define RDB(BUFB) {                                                         \
    _Pragma("unroll") for (int n2 = 0; n2 < 2; ++n2)                        \
      _Pragma("unroll") for (int kc = 0; kc < 4; ++kc) {                    \
        const char* b_ = lds + (BUFB) + 16384 + (kc >> 1) * 32768 +         \
                         wn * 4096 + n2 * 2048 +                            \
                         ((kc & 1) ? aoff_hi : aoff_lo);                    \
        fb[n2][kc] = *(const short8*)b_; } }

#define MF(MH) {                                                            \
    __builtin_amdgcn_s_setprio(1);                                          \
    _Pragma("unroll") for (int kc = 0; kc < 4; ++kc)                        \
      _Pragma("unroll") for (int m2 = 0; m2 < 2; ++m2)                      \
        _Pragma("unroll") for (int n2 = 0; n2 < 2; ++n2)                    \
          acc[(MH) * 2 + m2][n2] = __builtin_amdgcn_mfma_f32_32x32x16_bf16( \
              fa[m2][kc], fb[n2][kc], acc[(MH) * 2 + m2][n2], 0, 0, 0);     \
    __builtin_amdgcn_s_setprio(0); }

  // prologue: stage tile 0 into buffer 0
  STAGE4(0, 0);

  for (int t = 0; t < NT; ++t) {
    const int bufb = (t & 1) << 16;
    const int bufx = bufb ^ 65536;
    // ph1: drain own glls, rendezvous, consume mtiles 0,1 over full K=64
    VMC0();
    BAR();
    SB();
    RDB(bufb);
    RDA(bufb, 0);
    MF(0);
    // ph2: prefetch tile t+1 (no sync), consume mtiles 2,3
    if (t + 1 < NT) STAGE4(bufx, t + 1);
    RDA(bufb, 1);
    MF(1);
  }
#undef STAGE4
#undef RDA
#undef RDB
#undef MF

  BAR();   // staging planes dead; epilogue overlays buffer 0

  // -------- coalesced epilogue (per-wave 32x33-padded f32 slice) ----------
  float* wsl = (float*)(lds + w * 4352);       // 32 rows x stride 33 (4224B)
  const int rr2 = lane >> 1;                   // 0..31
  const int cb  = (lane & 1) * 16;             // 0 / 16

  float bvv[2];
#pragma unroll
  for (int n2 = 0; n2 < 2; ++n2)
    bvv[n2] = bias[(size_t)g * N + nt * 256 + wn * 64 + n2 * 32 + l31];

  const int rbase = (mt & 15) * 256;
  const int bsc = SECOND ? idx[g * 8 + (rbase >> 9)] : 0;
  const size_t obase = (size_t)bsc * S_DIM * D_DIM;

#pragma unroll
  for (int m2 = 0; m2 < 4; ++m2) {
#pragma unroll
    for (int n2 = 0; n2 < 2; ++n2) {
#pragma unroll
      for (int rg = 0; rg < 16; ++rg) {
        const int row = (rg & 3) + 8 * (rg >> 2) + 4 * khalf;
        float v = acc[m2][n2][rg] + bvv[n2];
        if (!SECOND) v = fmaxf(v, 0.0f);
        wsl[row * 33 + l31] = v;
      }
      const int gcol = nt * 256 + wn * 64 + n2 * 32 + cb;
      if constexpr (!SECOND) {
        const int grow = mt * 256 + wm * 128 + m2 * 32 + rr2;
        float4 v0 = *(const float4*)&wsl[rr2 * 33 + cb];
        float4 v1 = *(const float4*)&wsl[rr2 * 33 + cb + 4];
        float4 v2 = *(const float4*)&wsl[rr2 * 33 + cb + 8];
        float4 v3 = *(const float4*)&wsl[rr2 * 33 + cb + 12];
        __align__(16) __hip_bfloat16 ob[16];
        ob[0]=__float2bfloat16(v0.x); ob[1]=__float2bfloat16(v0.y);
        ob[2]=__float2bfloat16(v0.z); ob[3]=__float2bfloat16(v0.w);
        ob[4]=__float2bfloat16(v1.x); ob[5]=__float2bfloat16(v1.y);
        ob[6]=__float2bfloat16(v1.z); ob[7]=__float2bfloat16(v1.w);
        ob[8]=__float2bfloat16(v2.x); ob[9]=__float2bfloat16(v2.y);
        ob[10]=__float2bfloat16(v2.z); ob[11]=__float2bfloat16(v2.w);
        ob[12]=__float2bfloat16(v3.x); ob[13]=__float2bfloat16(v3.y);
        ob[14]=__float2bfloat16(v3.z); ob[15]=__float2bfloat16(v3.w);
        *(uint4*)&obf[(size_t)grow * N + gcol]     = *(const uint4*)&ob[0];
        *(uint4*)&obf[(size_t)grow * N + gcol + 8] = *(const uint4*)&ob[8];
      } else {
        const int rloc = rbase + wm * 128 + m2 * 32 + rr2;
        const int tok = rloc & 511;
        const size_t off = obase + (size_t)tok * D_DIM + gcol;
        float4 v0 = *(const float4*)&wsl[rr2 * 33 + cb];
        float4 v1 = *(const float4*)&wsl[rr2 * 33 + cb + 4];
        float4 v2 = *(const float4*)&wsl[rr2 * 33 + cb + 8];
        float4 v3 = *(const float4*)&wsl[rr2 * 33 + cb + 12];
        float4 x0 = *(const float4*)&xres[off];
        float4 x1 = *(const float4*)&xres[off + 4];
        float4 x2 = *(const float4*)&xres[off + 8];
        float4 x3 = *(const float4*)&xres[off + 12];
        v0.x+=x0.x; v0.y+=x0.y; v0.z+=x0.z; v0.w+=x0.w;
        v1.x+=x1.x; v1.y+=x1.y; v1.z+=x1.z; v1.w+=x1.w;
        v2.x+=x2.x; v2.y+=x2.y; v2.z+=x2.z; v2.w+=x2.w;
        v3.x+=x3.x; v3.y+=x3.y; v3.z+=x3.z; v3.w+=x3.w;
        *(float4*)&of32[off]      = v0;
        *(float4*)&of32[off + 4]  = v1;
        *(float4*)&of32[off + 8]  = v2;
        *(float4*)&of32[off + 12] = v3;
      }
    }
  }
}

// ---------------------------------------------------------------------------
extern "C" void kernel_launch(void* const* d_in, const int* in_sizes, int n_in,
                              void* d_out, int out_size, void* d_ws, size_t ws_size,
                              hipStream_t stream) {
  const float* x  = (const float*)d_in[0];
  const int*   idx = (const int*)d_in[1];
  const float* W1 = (const float*)d_in[2];
  const float* B1 = (const float*)d_in[3];
  const float* W2 = (const float*)d_in[4];
  const float* B2 = (const float*)d_in[5];
  const float* G  = (const float*)d_in[6];
  const float* Bn = (const float*)d_in[7];
  float* out = (float*)d_out;

  char* ws = (char*)d_ws;
  __hip_bfloat16* Xn  = (__hip_bfloat16*)(ws);                    // 32 MiB
  __hip_bfloat16* W1t = (__hip_bfloat16*)(ws + 33554432);         // 16 MiB
  __hip_bfloat16* W2t = (__hip_bfloat16*)(ws + 50331648);         // 16 MiB
  __hip_bfloat16* H1  = (__hip_bfloat16*)(ws + 67108864);         // 64 MiB

  (void)hipFuncSetAttribute((const void*)gemm_kernel<false>,
                            hipFuncAttributeMaxDynamicSharedMemorySize, 131072);
  (void)hipFuncSetAttribute((const void*)gemm_kernel<true>,
                            hipFuncAttributeMaxDynamicSharedMemorySize, 131072);

  prep_kernel<<<dim3(20480), dim3(256), 0, stream>>>(
      W1, W2, x, idx, G, Bn, W1t, W2t, Xn);
  gemm_kernel<false><<<dim3(512), dim3(512), 131072, stream>>>(
      Xn, W1t, B1, nullptr, nullptr, H1, nullptr, F_DIM, D_DIM, 16);
  gemm_kernel<true><<<dim3(256), dim3(512), 131072, stream>>>(
      H1, W2t, B2, x, idx, nullptr, out, D_DIM, F_DIM, 32);
}

// Round 10
// 188.357 us; speedup vs baseline: 1.1524x; 1.1522x over previous
//
#include <hip/hip_runtime.h>
#include <hip/hip_bf16.h>

// StackedAdapter: out[b] = x[b] + W2[g]^T·relu(W1[g]^T·LN(x[b]) + B1[g]) + B2[g]
// B=32, S=512, D=1024, F=2048. 16384 tokens, 4096 per group, 4 groups.
// Consolidated best (R6): 2-phase K-tile rhythm, permuted LDS planes
// (bank-conflict-free), 2 blocks/CU, coalesced epilogues, merged prep.

#define S_DIM 512
#define D_DIM 1024
#define F_DIM 2048
#define MPG   4096

typedef __attribute__((ext_vector_type(8))) short  short8;   // 8 bf16
typedef __attribute__((ext_vector_type(4))) float  f32x4;

__device__ __forceinline__ void gll16(const void* g, void* l) {
  __builtin_amdgcn_global_load_lds((__attribute__((address_space(1))) void*)g,
                                   (__attribute__((address_space(3))) void*)l,
                                   16, 0, 0);
}
#define VMC0()  asm volatile("s_waitcnt vmcnt(0)" ::: "memory")
#define SB()    __builtin_amdgcn_sched_barrier(0)
#define BAR()   __builtin_amdgcn_s_barrier()

// ---------------------------------------------------------------------------
// Kernel 1 (merged): weight transpose-cast  +  LayerNorm/gather.
//   blocks [0, 16384)    : W1/W2 [g][K][N] f32 -> [g][N][K] bf16 (32x32 tiles)
//   blocks [16384, 20480): LN + gather into group-major bf16 Xn
// ---------------------------------------------------------------------------
__global__ __launch_bounds__(256) void prep_kernel(
    const float* __restrict__ W1, const float* __restrict__ W2,
    const float* __restrict__ x,  const int* __restrict__ idx,
    const float* __restrict__ G,  const float* __restrict__ Bn,
    __hip_bfloat16* __restrict__ W1t, __hip_bfloat16* __restrict__ W2t,
    __hip_bfloat16* __restrict__ Xn)
{
  __shared__ float tl[32][33];
  const int bid = blockIdx.x;
  if (bid < 16384) {
    const float* src; __hip_bfloat16* dst;
    int R, C, tr, tc;
    if (bid < 8192) {                 // W1: [4][1024][2048] -> [4][2048][1024]
      const int g = bid >> 11, t = bid & 2047;
      R = 1024; C = 2048; tr = t >> 6; tc = t & 63;
      src = W1 + (size_t)g * R * C;
      dst = W1t + (size_t)g * R * C;
    } else {                          // W2: [4][2048][1024] -> [4][1024][2048]
      const int b2 = bid - 8192;
      const int g = b2 >> 11, t = b2 & 2047;
      R = 2048; C = 1024; tr = t >> 5; tc = t & 31;
      src = W2 + (size_t)g * R * C;
      dst = W2t + (size_t)g * R * C;
    }
    const int tx = threadIdx.x & 31, ty = threadIdx.x >> 5;
    const int r0 = tr * 32, c0 = tc * 32;
#pragma unroll
    for (int i = 0; i < 4; ++i)
      tl[ty + 8 * i][tx] = src[(size_t)(r0 + ty + 8 * i) * C + (c0 + tx)];
    __syncthreads();
#pragma unroll
    for (int i = 0; i < 4; ++i)
      dst[(size_t)(c0 + ty + 8 * i) * R + (r0 + tx)] = __float2bfloat16(tl[tx][ty + 8 * i]);
    return;
  }
  // ---- LayerNorm + gather ----
  const int lb   = bid - 16384;
  const int wid  = lb * 4 + (threadIdx.x >> 6);
  const int lane = threadIdx.x & 63;
  const int g = wid >> 12;
  const int r = wid & 4095;
  const int j = r >> 9;
  const int tok = r & 511;
  const int b = idx[g * 8 + j];

  const float* src = x + ((size_t)b * S_DIM + tok) * D_DIM + lane * 16;
  float4 vq[4];
#pragma unroll
  for (int i = 0; i < 4; ++i) vq[i] = ((const float4*)src)[i];
  const float* va = (const float*)vq;

  float s = 0.f, s2 = 0.f;
#pragma unroll
  for (int i = 0; i < 16; ++i) { s += va[i]; s2 += va[i] * va[i]; }
#pragma unroll
  for (int o = 32; o > 0; o >>= 1) { s += __shfl_xor(s, o); s2 += __shfl_xor(s2, o); }

  const float mu  = s * (1.0f / 1024.0f);
  float var = fmaxf(s2 * (1.0f / 1024.0f) - mu * mu, 0.0f) * (1024.0f / 1023.0f);
  const float rs  = 1.0f / (sqrtf(var) + 1e-6f);

  float4 gq[4], bq[4];
  const float* gp = G  + (size_t)g * D_DIM + lane * 16;
  const float* bp = Bn + (size_t)g * D_DIM + lane * 16;
#pragma unroll
  for (int i = 0; i < 4; ++i) { gq[i] = ((const float4*)gp)[i]; bq[i] = ((const float4*)bp)[i]; }
  const float* ga = (const float*)gq;
  const float* be = (const float*)bq;

  __align__(16) __hip_bfloat16 ob[16];
#pragma unroll
  for (int i = 0; i < 16; ++i)
    ob[i] = __float2bfloat16(ga[i] * (va[i] - mu) * rs + be[i]);

  __hip_bfloat16* dst = Xn + ((size_t)g * MPG + r) * D_DIM + lane * 16;
  ((uint4*)dst)[0] = *(const uint4*)&ob[0];
  ((uint4*)dst)[1] = *(const uint4*)&ob[8];
}

// ---------------------------------------------------------------------------
// Kernels 2/3: bf16 MFMA GEMM. BM=256, BN_ in {256,128}, BK=32, 8 waves
// (2M x 4N; per-wave 128 x BN_/4). LDS = 2 x (A 16KB + B BN_*64B) =
// 64KB (BN=256) / 48KB (BN=128)  =>  2 blocks per CU.
//
// Per K-tile (BK=32), 2-phase rhythm, ONE barrier + ONE vmcnt:
//   ph1: vmcnt(0) [own glls of tile t, issued during ph2(t-1)]; s_barrier;
//        read B frags (NFR) + A frags mh0; 4xNFR MFMA.
//   ph2: stage tile t+1 (A 2 gll + B 1-2 gll) into other buffer;
//        read A frags mh1; 4xNFR MFMA.      [no sync]
// Ordering: all tile t-1 reads of bufx precede the ph1(t) barrier; all
// tile t+1 writes to bufx follow it.
//
// Plane layout (verified R2-R7, SQ_LDS_BANK_CONFLICT=0): plane = rows x 32k,
// [lines of 128B = row-pair]; 16B-slot permutation
//   phys_slot(r,s) = ((r&1)*4+s) ^ ((r>>1)&7)
// applied on read side + inverse on per-lane global source; LDS dest linear.
// ---------------------------------------------------------------------------
template <int BN_, bool SECOND>
__global__ __launch_bounds__(512, 2) void gemm_kernel(
    const __hip_bfloat16* __restrict__ A,
    const __hip_bfloat16* __restrict__ Bw,
    const float* __restrict__ bias,
    const float* __restrict__ xres,
    const int* __restrict__ idx,
    __hip_bfloat16* __restrict__ obf,
    float* __restrict__ of32,
    const int N, const int K, const int NT)
{
  constexpr int APL  = 16384;          // A plane bytes (256 rows x 32k x 2B)
  constexpr int BPL  = BN_ * 64;       // B plane bytes
  constexpr int BUF  = APL + BPL;      // one K-tile buffer
  constexpr int NFR  = BN_ / 64;       // B frags per wave (4 or 2)
  constexpr int BROWS = BN_ / 8;       // B rows staged per wave (32 or 16)

  extern __shared__ char lds[];        // 2*BUF bytes
  const int ntile = N / BN_;
  const int nwg = gridDim.x;
  const int bid0 = blockIdx.x;
  const int bid = (bid0 & 7) * (nwg >> 3) + (bid0 >> 3);   // XCD-contiguous
  const int mt = bid / ntile, nt = bid % ntile;
  const int g  = mt >> 4;              // 4096/256 = 16 M-tiles per group
  const int tid = threadIdx.x;
  const int w = tid >> 6, lane = tid & 63;
  const int wm = w >> 2, wn = w & 3;

  const __hip_bfloat16* Ab = A + (size_t)mt * 256 * K;
  const __hip_bfloat16* Bb = Bw + ((size_t)g * N + (size_t)nt * BN_) * K;

  // staging decode: inverse slot permutation on the global source address
  const int sp   = (lane & 7) ^ ((lane >> 3) & 7);
  const int srow = 2 * (lane >> 3) + (sp >> 2);
  const int skof = (sp & 3) * 8;
  const __hip_bfloat16* Ag0 = Ab + (size_t)(w * 32 + srow) * K + skof;
  const __hip_bfloat16* Ag1 = Ag0 + (size_t)16 * K;
  const __hip_bfloat16* Bg0 = Bb + (size_t)(w * BROWS + srow) * K + skof;
  const __hip_bfloat16* Bg1 = Bg0 + (size_t)16 * K;   // used when BN_==256

  // read-side lane constant (physical slot)
  const int l15 = lane & 15, sl = lane >> 4;
  const int slot_phys = (((l15 & 1) << 2) + sl) ^ ((l15 >> 1) & 7);
  const int lane_c = ((l15 >> 1) << 7) + (slot_phys << 4);

  f32x4 acc[8][NFR] = {};
  short8 frA[4], frB[NFR];

  // stage both planes of K-tile TN into buffer at byte offset BUFX
#define STAGE(BUFX, TN) {                                                   \
    const int k0 = (TN) * 32;                                               \
    char* dA = lds + (BUFX) + w * 2048;                                     \
    gll16(Ag0 + k0, dA); gll16(Ag1 + k0, dA + 1024);                        \
    char* dB = lds + (BUFX) + APL + w * (BROWS * 64);                       \
    gll16(Bg0 + k0, dB);                                                    \
    if (BN_ == 256) gll16(Bg1 + k0, dB + 1024); }

#define RDA(BUFB, MH) {                                                     \
    const char* b_ = lds + (BUFB) + wm * 8192 + (MH) * 4096 + lane_c;       \
    _Pragma("unroll") for (int mm = 0; mm < 4; ++mm)                        \
      frA[mm] = *(const short8*)(b_ + mm * 1024); }

#define RDB(BUFB) {                                                         \
    const char* b_ = lds + (BUFB) + APL + wn * (BPL / 4) + lane_c;          \
    _Pragma("unroll") for (int n = 0; n < NFR; ++n)                         \
      frB[n] = *(const short8*)(b_ + n * 1024); }

#define MF(MH) {                                                            \
    __builtin_amdgcn_s_setprio(1);                                          \
    _Pragma("unroll") for (int mm = 0; mm < 4; ++mm)                        \
      _Pragma("unroll") for (int n = 0; n < NFR; ++n)                       \
        acc[(MH) * 4 + mm][n] = __builtin_amdgcn_mfma_f32_16x16x32_bf16(    \
            frA[mm], frB[n], acc[(MH) * 4 + mm][n], 0, 0, 0);               \
    __builtin_amdgcn_s_setprio(0); }

  // prologue: stage tile 0 into buffer 0
  STAGE(0, 0);

  for (int t = 0; t < NT; ++t) {
    const int bufb = (t & 1) ? BUF : 0;
    const int bufx = (t & 1) ? 0 : BUF;
    // ph1: drain own glls, rendezvous, consume mh0
    VMC0();
    BAR();
    SB();
    RDB(bufb);
    RDA(bufb, 0);
    MF(0);
    // ph2: prefetch tile t+1 (no sync), consume mh1
    if (t + 1 < NT) STAGE(bufx, t + 1);
    RDA(bufb, 1);
    MF(1);
  }
#undef STAGE
#undef RDA
#undef RDB
#undef MF

  // all waves done reading staging planes before epilogue overlays them
  BAR();

  // -------- coalesced epilogue (per-wave private LDS slice) ---------------
  // C/D layout: col = lane&15, row = (lane>>4)*4 + i   [m89/m91]
  const int cc  = lane & 15;
  const int cr4 = (lane >> 4) * 4;

  float bv[NFR];
#pragma unroll
  for (int n = 0; n < NFR; ++n)
    bv[n] = bias[(size_t)g * N + nt * BN_ + wn * (BN_ / 4) + n * 16 + cc];

  float* wsl = (float*)(lds + w * 4352);     // 16 rows x stride 68 f32
  constexpr int CG  = BN_ / 32;              // lanes per row-slice (8 or 4)
  constexpr int RIT = CG / 4;                // row iterations (2 or 1)
  const int rr  = lane / CG;
  const int c8  = (lane % CG) * 8;
  const int gcol0 = nt * BN_ + wn * (BN_ / 4) + c8;

  if constexpr (!SECOND) {
    // H1 = relu(acc + bias) -> bf16, rows in group-gathered order
#pragma unroll
    for (int p = 0; p < 8; ++p) {
#pragma unroll
      for (int n = 0; n < NFR; ++n)
#pragma unroll
        for (int i = 0; i < 4; ++i)
          wsl[(cr4 + i) * 68 + n * 16 + cc] = fmaxf(acc[p][n][i] + bv[n], 0.0f);
      const int grow0 = mt * 256 + wm * 128 + p * 16;
#pragma unroll
      for (int it = 0; it < RIT; ++it) {
        const int r = it * (64 / CG) + rr;
        float4 v0 = *(const float4*)&wsl[r * 68 + c8];
        float4 v1 = *(const float4*)&wsl[r * 68 + c8 + 4];
        __align__(16) __hip_bfloat16 ob[8];
        ob[0] = __float2bfloat16(v0.x); ob[1] = __float2bfloat16(v0.y);
        ob[2] = __float2bfloat16(v0.z); ob[3] = __float2bfloat16(v0.w);
        ob[4] = __float2bfloat16(v1.x); ob[5] = __float2bfloat16(v1.y);
        ob[6] = __float2bfloat16(v1.z); ob[7] = __float2bfloat16(v1.w);
        *(uint4*)&obf[(size_t)(grow0 + r) * N + gcol0] = *(const uint4*)ob;
      }
    }
  } else {
    // out = acc + bias + xres, scattered to original batch rows (f32)
    const int rbase = (mt & 15) * 256;
    const int b = idx[g * 8 + (rbase >> 9)];
    const size_t ob = (size_t)b * S_DIM * D_DIM;
#pragma unroll
    for (int p = 0; p < 8; ++p) {
#pragma unroll
      for (int n = 0; n < NFR; ++n)
#pragma unroll
        for (int i = 0; i < 4; ++i)
          wsl[(cr4 + i) * 68 + n * 16 + cc] = acc[p][n][i] + bv[n];
      const int rloc0 = rbase + wm * 128 + p * 16;
#pragma unroll
      for (int it = 0; it < RIT; ++it) {
        const int r = it * (64 / CG) + rr;
        const int tok = (rloc0 + r) & 511;
        const size_t off = ob + (size_t)tok * D_DIM + gcol0;
        float4 v0 = *(const float4*)&wsl[r * 68 + c8];
        float4 v1 = *(const float4*)&wsl[r * 68 + c8 + 4];
        float4 x0 = *(const float4*)&xres[off];
        float4 x1 = *(const float4*)&xres[off + 4];
        v0.x += x0.x; v0.y += x0.y; v0.z += x0.z; v0.w += x0.w;
        v1.x += x1.x; v1.y += x1.y; v1.z += x1.z; v1.w += x1.w;
        *(float4*)&of32[off]     = v0;
        *(float4*)&of32[off + 4] = v1;
      }
    }
  }
}

// ---------------------------------------------------------------------------
extern "C" void kernel_launch(void* const* d_in, const int* in_sizes, int n_in,
                              void* d_out, int out_size, void* d_ws, size_t ws_size,
                              hipStream_t stream) {
  const float* x  = (const float*)d_in[0];
  const int*   idx = (const int*)d_in[1];
  const float* W1 = (const float*)d_in[2];
  const float* B1 = (const float*)d_in[3];
  const float* W2 = (const float*)d_in[4];
  const float* B2 = (const float*)d_in[5];
  const float* G  = (const float*)d_in[6];
  const float* Bn = (const float*)d_in[7];
  float* out = (float*)d_out;

  char* ws = (char*)d_ws;
  __hip_bfloat16* Xn  = (__hip_bfloat16*)(ws);                    // 32 MiB
  __hip_bfloat16* W1t = (__hip_bfloat16*)(ws + 33554432);         // 16 MiB
  __hip_bfloat16* W2t = (__hip_bfloat16*)(ws + 50331648);         // 16 MiB
  __hip_bfloat16* H1  = (__hip_bfloat16*)(ws + 67108864);         // 64 MiB

  (void)hipFuncSetAttribute((const void*)gemm_kernel<256, false>,
                            hipFuncAttributeMaxDynamicSharedMemorySize, 65536);
  (void)hipFuncSetAttribute((const void*)gemm_kernel<128, true>,
                            hipFuncAttributeMaxDynamicSharedMemorySize, 49152);

  prep_kernel<<<dim3(20480), dim3(256), 0, stream>>>(
      W1, W2, x, idx, G, Bn, W1t, W2t, Xn);
  // GEMM1: 256x256 tile -> (16384/256)*(2048/256) = 512 blocks = 2/CU
  gemm_kernel<256, false><<<dim3(512), dim3(512), 65536, stream>>>(
      Xn, W1t, B1, nullptr, nullptr, H1, nullptr, F_DIM, D_DIM, 32);
  // GEMM2: 256x128 tile -> (16384/256)*(1024/128) = 512 blocks = 2/CU
  gemm_kernel<128, true><<<dim3(512), dim3(512), 49152, stream>>>(
      H1, W2t, B2, x, idx, nullptr, out, D_DIM, F_DIM, 64);
}

// Round 11
// 171.467 us; speedup vs baseline: 1.2659x; 1.0985x over previous
//
#include <hip/hip_runtime.h>
#include <hip/hip_bf16.h>

// StackedAdapter: out[b] = x[b] + W2[g]^T·relu(W1[g]^T·LN(x[b]) + B1[g]) + B2[g]
// B=32, S=512, D=1024, F=2048. 16384 tokens, 4096 per group, 4 groups.
// TRUE R6 restore (best measured: 171.2 µs): merged prep; GEMMs 256x256,
// BK=64, 128 KiB dbuf, 2-phase rhythm (1 barrier + 1 vmcnt(0) per K-tile),
// permuted conflict-free LDS planes, coalesced epilogues.

#define S_DIM 512
#define D_DIM 1024
#define F_DIM 2048
#define MPG   4096

typedef __attribute__((ext_vector_type(8))) short  short8;   // 8 bf16
typedef __attribute__((ext_vector_type(4))) float  f32x4;

__device__ __forceinline__ void gll16(const void* g, void* l) {
  __builtin_amdgcn_global_load_lds((__attribute__((address_space(1))) void*)g,
                                   (__attribute__((address_space(3))) void*)l,
                                   16, 0, 0);
}
#define VMC0()  asm volatile("s_waitcnt vmcnt(0)" ::: "memory")
#define SB()    __builtin_amdgcn_sched_barrier(0)
#define BAR()   __builtin_amdgcn_s_barrier()

// ---------------------------------------------------------------------------
// Kernel 1 (merged): weight transpose-cast  +  LayerNorm/gather.
//   blocks [0, 16384)    : W1/W2 [g][K][N] f32 -> [g][N][K] bf16 (32x32 tiles)
//   blocks [16384, 20480): LN + gather into group-major bf16 Xn
// ---------------------------------------------------------------------------
__global__ __launch_bounds__(256) void prep_kernel(
    const float* __restrict__ W1, const float* __restrict__ W2,
    const float* __restrict__ x,  const int* __restrict__ idx,
    const float* __restrict__ G,  const float* __restrict__ Bn,
    __hip_bfloat16* __restrict__ W1t, __hip_bfloat16* __restrict__ W2t,
    __hip_bfloat16* __restrict__ Xn)
{
  __shared__ float tl[32][33];
  const int bid = blockIdx.x;
  if (bid < 16384) {
    const float* src; __hip_bfloat16* dst;
    int R, C, tr, tc;
    if (bid < 8192) {                 // W1: [4][1024][2048] -> [4][2048][1024]
      const int g = bid >> 11, t = bid & 2047;
      R = 1024; C = 2048; tr = t >> 6; tc = t & 63;
      src = W1 + (size_t)g * R * C;
      dst = W1t + (size_t)g * R * C;
    } else {                          // W2: [4][2048][1024] -> [4][1024][2048]
      const int b2 = bid - 8192;
      const int g = b2 >> 11, t = b2 & 2047;
      R = 2048; C = 1024; tr = t >> 5; tc = t & 31;
      src = W2 + (size_t)g * R * C;
      dst = W2t + (size_t)g * R * C;
    }
    const int tx = threadIdx.x & 31, ty = threadIdx.x >> 5;
    const int r0 = tr * 32, c0 = tc * 32;
#pragma unroll
    for (int i = 0; i < 4; ++i)
      tl[ty + 8 * i][tx] = src[(size_t)(r0 + ty + 8 * i) * C + (c0 + tx)];
    __syncthreads();
#pragma unroll
    for (int i = 0; i < 4; ++i)
      dst[(size_t)(c0 + ty + 8 * i) * R + (r0 + tx)] = __float2bfloat16(tl[tx][ty + 8 * i]);
    return;
  }
  // ---- LayerNorm + gather ----
  const int lb   = bid - 16384;
  const int wid  = lb * 4 + (threadIdx.x >> 6);
  const int lane = threadIdx.x & 63;
  const int g = wid >> 12;
  const int r = wid & 4095;
  const int j = r >> 9;
  const int tok = r & 511;
  const int b = idx[g * 8 + j];

  const float* src = x + ((size_t)b * S_DIM + tok) * D_DIM + lane * 16;
  float4 vq[4];
#pragma unroll
  for (int i = 0; i < 4; ++i) vq[i] = ((const float4*)src)[i];
  const float* va = (const float*)vq;

  float s = 0.f, s2 = 0.f;
#pragma unroll
  for (int i = 0; i < 16; ++i) { s += va[i]; s2 += va[i] * va[i]; }
#pragma unroll
  for (int o = 32; o > 0; o >>= 1) { s += __shfl_xor(s, o); s2 += __shfl_xor(s2, o); }

  const float mu  = s * (1.0f / 1024.0f);
  float var = fmaxf(s2 * (1.0f / 1024.0f) - mu * mu, 0.0f) * (1024.0f / 1023.0f);
  const float rs  = 1.0f / (sqrtf(var) + 1e-6f);

  float4 gq[4], bq[4];
  const float* gp = G  + (size_t)g * D_DIM + lane * 16;
  const float* bp = Bn + (size_t)g * D_DIM + lane * 16;
#pragma unroll
  for (int i = 0; i < 4; ++i) { gq[i] = ((const float4*)gp)[i]; bq[i] = ((const float4*)bp)[i]; }
  const float* ga = (const float*)gq;
  const float* be = (const float*)bq;

  __align__(16) __hip_bfloat16 ob[16];
#pragma unroll
  for (int i = 0; i < 16; ++i)
    ob[i] = __float2bfloat16(ga[i] * (va[i] - mu) * rs + be[i]);

  __hip_bfloat16* dst = Xn + ((size_t)g * MPG + r) * D_DIM + lane * 16;
  ((uint4*)dst)[0] = *(const uint4*)&ob[0];
  ((uint4*)dst)[1] = *(const uint4*)&ob[8];
}

// ---------------------------------------------------------------------------
// Kernels 2/3: bf16 MFMA GEMM, 256x256 tile, BK=64, 8 waves (2Mx4N).
// TWO phases per K-tile, ONE barrier + ONE vmcnt per K-tile:
//   ph1: vmcnt(0) [tile t's 8 glls, issued 1 K-tile earlier => covered];
//        s_barrier; sched_barrier; read B frags (both kh, held in regs) +
//        A frags MH0; 32-MFMA cluster (MH0).
//   ph2: stage ALL 4 planes of tile t+1 into the other buffer (8 gll);
//        read A frags MH1; 32-MFMA cluster (MH1).   [no sync at all]
// Publish rule: own-vmcnt BEFORE the barrier. Staging bufx at ph2(t) races
// nothing: bufx's previous readers (tile t-1) finished before this tile's
// barrier. ds ops cannot hoist above the barrier (SB) or sink across the
// memory-clobber vmcnt asm.
//
// LDS 2x64KB buffers, 4 planes {A kh0, B kh0, A kh1, B kh1} @ 16KB each.
// Plane = [128 lines][128B], line = row-pair; 16B-slot permutation
//   phys_slot(r,s) = ((r&1)*4+s) ^ ((r>>1)&7)
// on read side + inverse on per-lane global source; LDS dest linear
// (rule 21). Conflict-free (R2-R6: SQ_LDS_BANK_CONFLICT ~ 0).
// NT even => last tile reads buffer1 only; buffer0 free for epilogue.
// ---------------------------------------------------------------------------
template <bool SECOND>
__global__ __launch_bounds__(512, 2) void gemm_kernel(
    const __hip_bfloat16* __restrict__ A,
    const __hip_bfloat16* __restrict__ Bw,
    const float* __restrict__ bias,
    const float* __restrict__ xres,
    const int* __restrict__ idx,
    __hip_bfloat16* __restrict__ obf,
    float* __restrict__ of32,
    const int N, const int K, const int NT)
{
  extern __shared__ char lds[];     // 131072 bytes
  const int ntile = N >> 8;
  const int nwg = gridDim.x;
  const int bid0 = blockIdx.x;
  const int bid = (bid0 & 7) * (nwg >> 3) + (bid0 >> 3);   // XCD-contiguous
  const int mt = bid / ntile, nt = bid % ntile;
  const int g  = mt >> 4;
  const int tid = threadIdx.x;
  const int w = tid >> 6, lane = tid & 63;
  const int wm = w >> 2, wn = w & 3;

  const __hip_bfloat16* Ab = A + (size_t)mt * 256 * K;
  const __hip_bfloat16* Bb = Bw + ((size_t)g * N + (size_t)nt * 256) * K;

  // staging decode: inverse slot permutation on the global source address
  const int sp   = (lane & 7) ^ ((lane >> 3) & 7);
  const int srow = 2 * (lane >> 3) + (sp >> 2);
  const int skof = (sp & 3) * 8;
  const __hip_bfloat16* Ag0 = Ab + (size_t)(w * 32 + srow) * K + skof;
  const __hip_bfloat16* Ag1 = Ag0 + (size_t)16 * K;
  const __hip_bfloat16* Bg0 = Bb + (size_t)(w * 32 + srow) * K + skof;
  const __hip_bfloat16* Bg1 = Bg0 + (size_t)16 * K;

  // read-side lane constant (physical slot)
  const int l15 = lane & 15, sl = lane >> 4;
  const int slot_phys = (((l15 & 1) << 2) + sl) ^ ((l15 >> 1) & 7);
  const int lane_c = ((l15 >> 1) << 7) + (slot_phys << 4);

  f32x4 acc[8][4] = {};
  short8 frA[2][4], frB[2][4];

  // stage all 4 planes (A kh0, B kh0, A kh1, B kh1) of K-tile TN into BUFX
#define STAGE4(BUFX, TN) {                                                  \
    const int k0 = (TN) * 64;                                               \
    char* d0 = lds + (BUFX) + w * 2048;                                     \
    gll16(Ag0 + k0,      d0);         gll16(Ag1 + k0,      d0 + 1024);      \
    gll16(Bg0 + k0,      d0 + 16384); gll16(Bg1 + k0,      d0 + 17408);     \
    gll16(Ag0 + k0 + 32, d0 + 32768); gll16(Ag1 + k0 + 32, d0 + 33792);     \
    gll16(Bg0 + k0 + 32, d0 + 49152); gll16(Bg1 + k0 + 32, d0 + 50176); }

#define RDA2(BUFB, MH) {                                                    \
    _Pragma("unroll") for (int kh = 0; kh < 2; ++kh) {                      \
      const char* b_ = lds + (BUFB) + kh * 32768 + wm * 8192 +              \
                       (MH) * 4096 + lane_c;                                \
      _Pragma("unroll") for (int mm = 0; mm < 4; ++mm)                      \
        frA[kh][mm] = *(const short8*)(b_ + mm * 1024); } }

#define RDB2(BUFB) {                                                        \
    _Pragma("unroll") for (int kh = 0; kh < 2; ++kh) {                      \
      const char* b_ = lds + (BUFB) + 16384 + kh * 32768 + wn * 4096 +      \
                       lane_c;                                              \
      _Pragma("unroll") for (int n = 0; n < 4; ++n)                         \
        frB[kh][n] = *(const short8*)(b_ + n * 1024); } }

#define MF32(MH) {                                                          \
    __builtin_amdgcn_s_setprio(1);                                          \
    _Pragma("unroll") for (int kh = 0; kh < 2; ++kh)                        \
      _Pragma("unroll") for (int mm = 0; mm < 4; ++mm)                      \
        _Pragma("unroll") for (int n = 0; n < 4; ++n)                       \
          acc[(MH) * 4 + mm][n] = __builtin_amdgcn_mfma_f32_16x16x32_bf16(  \
              frA[kh][mm], frB[kh][n], acc[(MH) * 4 + mm][n], 0, 0, 0);     \
    __builtin_amdgcn_s_setprio(0); }

  // prologue: stage tile 0 into buffer 0
  STAGE4(0, 0);

  for (int t = 0; t < NT; ++t) {
    const int bufb = (t & 1) << 16;
    const int bufx = bufb ^ 65536;
    // ph1: drain own glls, rendezvous, consume MH0 over full K=64
    VMC0();
    BAR();
    SB();
    RDB2(bufb);
    RDA2(bufb, 0);
    MF32(0);
    // ph2: prefetch tile t+1 (no sync), consume MH1
    if (t + 1 < NT) STAGE4(bufx, t + 1);
    RDA2(bufb, 1);
    MF32(1);
  }
#undef STAGE4
#undef RDA2
#undef RDB2
#undef MF32

  // -------- coalesced epilogue (per-wave private LDS slice in buffer 0) ----
  // NT even => last tile read buffer 1 (bytes 65536+); epilogue slices
  // (w*4352, 8x4352 = 34816 B) live in buffer 0: disjoint, no barrier needed.
  // C/D layout: col = lane&15, row = (lane>>4)*4 + i   [m89/m91]
  const int cc  = lane & 15;
  const int cr4 = (lane >> 4) * 4;

  float bv[4];
#pragma unroll
  for (int n = 0; n < 4; ++n)
    bv[n] = bias[(size_t)g * N + nt * 256 + wn * 64 + n * 16 + cc];

  float* wsl = (float*)(lds + w * 4352);     // 16 rows x stride 68 f32
  const int rr  = lane >> 3;                 // 0..7
  const int c8  = (lane & 7) * 8;            // 0..56
  const int gcol0 = nt * 256 + wn * 64 + c8;

  if constexpr (!SECOND) {
    // H1 = relu(acc + bias) -> bf16, rows in group-gathered order
#pragma unroll
    for (int p = 0; p < 8; ++p) {
#pragma unroll
      for (int n = 0; n < 4; ++n)
#pragma unroll
        for (int i = 0; i < 4; ++i)
          wsl[(cr4 + i) * 68 + n * 16 + cc] = fmaxf(acc[p][n][i] + bv[n], 0.0f);
      const int grow0 = mt * 256 + wm * 128 + p * 16;
#pragma unroll
      for (int it = 0; it < 2; ++it) {
        const int r = it * 8 + rr;
        float4 v0 = *(const float4*)&wsl[r * 68 + c8];
        float4 v1 = *(const float4*)&wsl[r * 68 + c8 + 4];
        __align__(16) __hip_bfloat16 ob[8];
        ob[0] = __float2bfloat16(v0.x); ob[1] = __float2bfloat16(v0.y);
        ob[2] = __float2bfloat16(v0.z); ob[3] = __float2bfloat16(v0.w);
        ob[4] = __float2bfloat16(v1.x); ob[5] = __float2bfloat16(v1.y);
        ob[6] = __float2bfloat16(v1.z); ob[7] = __float2bfloat16(v1.w);
        *(uint4*)&obf[(size_t)(grow0 + r) * N + gcol0] = *(const uint4*)ob;
      }
    }
  } else {
    // out = acc + bias + xres, scattered to original batch rows (f32)
    const int rbase = (mt & 15) * 256;
    const int b = idx[g * 8 + (rbase >> 9)];
    const size_t ob = (size_t)b * S_DIM * D_DIM;
#pragma unroll
    for (int p = 0; p < 8; ++p) {
#pragma unroll
      for (int n = 0; n < 4; ++n)
#pragma unroll
        for (int i = 0; i < 4; ++i)
          wsl[(cr4 + i) * 68 + n * 16 + cc] = acc[p][n][i] + bv[n];
      const int rloc0 = rbase + wm * 128 + p * 16;
#pragma unroll
      for (int it = 0; it < 2; ++it) {
        const int r = it * 8 + rr;
        const int tok = (rloc0 + r) & 511;
        const size_t off = ob + (size_t)tok * D_DIM + gcol0;
        float4 v0 = *(const float4*)&wsl[r * 68 + c8];
        float4 v1 = *(const float4*)&wsl[r * 68 + c8 + 4];
        float4 x0 = *(const float4*)&xres[off];
        float4 x1 = *(const float4*)&xres[off + 4];
        v0.x += x0.x; v0.y += x0.y; v0.z += x0.z; v0.w += x0.w;
        v1.x += x1.x; v1.y += x1.y; v1.z += x1.z; v1.w += x1.w;
        *(float4*)&of32[off]     = v0;
        *(float4*)&of32[off + 4] = v1;
      }
    }
  }
}

// ---------------------------------------------------------------------------
extern "C" void kernel_launch(void* const* d_in, const int* in_sizes, int n_in,
                              void* d_out, int out_size, void* d_ws, size_t ws_size,
                              hipStream_t stream) {
  const float* x  = (const float*)d_in[0];
  const int*   idx = (const int*)d_in[1];
  const float* W1 = (const float*)d_in[2];
  const float* B1 = (const float*)d_in[3];
  const float* W2 = (const float*)d_in[4];
  const float* B2 = (const float*)d_in[5];
  const float* G  = (const float*)d_in[6];
  const float* Bn = (const float*)d_in[7];
  float* out = (float*)d_out;

  char* ws = (char*)d_ws;
  __hip_bfloat16* Xn  = (__hip_bfloat16*)(ws);                    // 32 MiB
  __hip_bfloat16* W1t = (__hip_bfloat16*)(ws + 33554432);         // 16 MiB
  __hip_bfloat16* W2t = (__hip_bfloat16*)(ws + 50331648);         // 16 MiB
  __hip_bfloat16* H1  = (__hip_bfloat16*)(ws + 67108864);         // 64 MiB

  (void)hipFuncSetAttribute((const void*)gemm_kernel<false>,
                            hipFuncAttributeMaxDynamicSharedMemorySize, 131072);
  (void)hipFuncSetAttribute((const void*)gemm_kernel<true>,
                            hipFuncAttributeMaxDynamicSharedMemorySize, 131072);

  prep_kernel<<<dim3(20480), dim3(256), 0, stream>>>(
      W1, W2, x, idx, G, Bn, W1t, W2t, Xn);
  gemm_kernel<false><<<dim3(512), dim3(512), 131072, stream>>>(
      Xn, W1t, B1, nullptr, nullptr, H1, nullptr, F_DIM, D_DIM, 16);
  gemm_kernel<true><<<dim3(256), dim3(512), 131072, stream>>>(
      H1, W2t, B2, x, idx, nullptr, out, D_DIM, F_DIM, 32);
}